// Round 11
// baseline (120.014 us; speedup 1.0000x reference)
//
#include <hip/hip_runtime.h>
#include <hip/hip_bf16.h>

// Attention fwd with materialized p_attn.
// B=16, S=2048, D=64, f32 in/out. d_out = [out (B,S,D) | p_attn (B,S,S)] f32.
#define BN 16
#define SN 2048
#define DN 64
#define QB 16
#define NWAVE 8           // 512 threads
#define KSEG 256          // keys per wave
#define NCH 8             // chunks (32 keys) per wave

#define SC_L2E 0.18033688011112042f   // 0.125 * log2(e)
#define BI_L2E 11.541560327111707f    // 8 * log2(e): p~ = exp(s - 8)

typedef __attribute__((ext_vector_type(8))) short bf16x8;
typedef __attribute__((ext_vector_type(4))) short bf16x4;
typedef __attribute__((ext_vector_type(4))) float f32x4;
typedef __attribute__((ext_vector_type(4))) int   i32x4;

static __device__ __forceinline__ short f2bf(float f) {
    __hip_bfloat16 h = __float2bfloat16(f);
    union { __hip_bfloat16 h; short s; } u; u.h = h;
    return u.s;
}
static __device__ __forceinline__ float uf(unsigned u) {
    union { unsigned u; float f; } v; v.u = u;
    return v.f;
}
static __device__ __forceinline__ unsigned pk2(float lo, float hi) {
    return ((unsigned)(unsigned short)f2bf(lo)) |
           (((unsigned)(unsigned short)f2bf(hi)) << 16);
}
static __device__ __forceinline__ float fast_exp2(float x) {
#if __has_builtin(__builtin_amdgcn_exp2f)
    return __builtin_amdgcn_exp2f(x);
#else
    return exp2f(x);
#endif
}

// ---- prep: swizzle K and V into MFMA-fragment lane order; mask -> f32 bias ----
// (unchanged from R10 — validated)
__global__ __launch_bounds__(256)
void prep_kv(const float* __restrict__ K, const float* __restrict__ V,
             const int* __restrict__ M,
             short* __restrict__ Kf, short* __restrict__ Vf, float* __restrict__ Mf)
{
    __shared__ short vt[64][72];
    const int b   = blockIdx.x >> 5;
    const int s0  = (blockIdx.x & 31) << 6;
    const int cg0 = s0 >> 5;
    const int tid = threadIdx.x;
    const int sr = tid >> 4;
    const int dc = (tid & 15) << 2;
    #pragma unroll
    for (int i = 0; i < 4; ++i) {
        const int s = sr + i * 16;
        f32x4 vv = *(const f32x4*)(V + ((size_t)b * SN + s0 + s) * DN + dc);
        bf16x4 v4;
        #pragma unroll
        for (int j = 0; j < 4; ++j) v4[j] = f2bf(vv[j]);
        *(bf16x4*)&vt[s][dc] = v4;
    }
    if (tid < 64) {
        const int m = M[(size_t)b * SN + s0 + tid];
        Mf[(size_t)b * SN + s0 + tid] = m ? -BI_L2E : -1e9f;
    }
    __syncthreads();

    #pragma unroll
    for (int r = 0; r < 2; ++r) {
        const int o   = tid + (r << 8);
        const int h   = o >> 8;
        const int s   = (o >> 6) & 3;
        const int l2  = o & 63;
        const int lq2 = l2 & 15, lg2 = l2 >> 4;
        const int srow = s0 + h * 32 + ((s >> 1) & 1) * 16 + lq2;
        const int scol = (s & 1) * 32 + lg2 * 8;
        const float* kp = K + ((size_t)b * SN + srow) * DN + scol;
        f32x4 x = *(const f32x4*)kp;
        f32x4 y = *(const f32x4*)(kp + 4);
        bf16x8 kv;
        #pragma unroll
        for (int j = 0; j < 4; ++j) { kv[j] = f2bf(x[j]); kv[4 + j] = f2bf(y[j]); }
        *(bf16x8*)(Kf + (size_t)(((b * 64 + cg0 + h) * 4 + s) * 512 + l2 * 8)) = kv;
    }
    #pragma unroll
    for (int r = 0; r < 2; ++r) {
        const int o   = tid + (r << 8);
        const int h   = o >> 8;
        const int nt  = (o >> 6) & 3;
        const int l2  = o & 63;
        const int lq2 = l2 & 15, lg2 = l2 >> 4;
        const int d   = nt * 16 + lq2;
        bf16x8 w;
        #pragma unroll
        for (int j = 0; j < 4; ++j) {
            w[j]     = vt[h * 32 + 4 * lg2 + j][d];
            w[4 + j] = vt[h * 32 + 16 + 4 * lg2 + j][d];
        }
        *(bf16x8*)(Vf + (size_t)(((b * 64 + cg0 + h) * 4 + nt) * 512 + l2 * 8)) = w;
    }
}

// ---- fused attention: single main loop (QK^T + exp + PV), store tail ----
// Per chunk: load Kf/Vf frags (lane-contiguous dwordx4) -> QK^T mfma(K,Q) ->
// exp -> pack pk[c] -> in-place PV (slot-permuted A; Vf layout matches).
// PV needs no row sum -> ALL MFMA work before the single barrier.
// Tail: rl from lred, 16 NT f32x4 p-stores from regs, O reduce + write.
template <int PRE>
__global__ __launch_bounds__(512, 2)
void attn_fused(const float* __restrict__ Q, const float* __restrict__ K,
                const float* __restrict__ V, const int* __restrict__ M,
                const short* __restrict__ Kf, const short* __restrict__ Vf,
                const float* __restrict__ Mf, float* __restrict__ out)
{
    __shared__ float obuf[NWAVE * QB * DN];   // 32 KB (epilogue only)
    __shared__ float lred[NWAVE * QB];
    __shared__ float lfin[QB];

    const int tid = threadIdx.x;
    const int wv = tid >> 6, ln = tid & 63;
    const int lq = ln & 15, lg = ln >> 4;

    // XCD-bijective swizzle (2048 blocks / 8 XCDs): 2 batches per XCD.
    const int lb = ((blockIdx.x & 7) << 8) | (blockIdx.x >> 3);
    const int bb = lb >> 7;
    const int q0 = (lb & 127) << 4;

    const float* Qb = Q + ((size_t)bb * SN + q0) * DN;
    float* out_o = out + ((size_t)bb * SN + q0) * DN;
    float* out_p = out + (size_t)BN * SN * DN + ((size_t)bb * SN + q0) * SN;

    // Q fragment (B-operand of swapped QK^T): Q[col=lq][d=8*lg+j]
    bf16x8 qf0, qf1;
    {
        const float* src = Qb + lq * DN + lg * 8;
        f32x4 a = *(const f32x4*)src;
        f32x4 b = *(const f32x4*)(src + 4);
        f32x4 c = *(const f32x4*)(src + 32);
        f32x4 d = *(const f32x4*)(src + 36);
        #pragma unroll
        for (int j = 0; j < 4; ++j) {
            qf0[j] = f2bf(a[j]); qf0[4 + j] = f2bf(b[j]);
            qf1[j] = f2bf(c[j]); qf1[4 + j] = f2bf(d[j]);
        }
    }

    const int k0 = wv * KSEG;
    const int cgb = bb * 64 + wv * NCH;
    const short* kfp = Kf + (size_t)cgb * 2048 + ln * 8;
    const short* vfp = Vf + (size_t)cgb * 2048 + ln * 8;
    const float* fp  = Mf + (size_t)bb * SN + k0 + 4 * lg;
    const int*   Mb  = M + (size_t)bb * SN;
    const float* Kb  = K + (size_t)bb * SN * DN;
    const float* Vb  = V + (size_t)bb * SN * DN;

    unsigned pk[NCH][4];
    f32x4 oacc[4];
    #pragma unroll
    for (int nt = 0; nt < 4; ++nt) oacc[nt] = (f32x4){0.f, 0.f, 0.f, 0.f};
    float lsum = 0.f;

    // ================= single main loop: QK^T + exp + PV =================
    #pragma unroll
    for (int c = 0; c < NCH; ++c) {
        bf16x8 kf0, kf1, kf2, kf3, vf0, vf1, vf2, vf3;
        f32x4 b0, b1;
        if constexpr (PRE) {
            kf0 = *(const bf16x8*)(kfp + c * 2048);
            kf1 = *(const bf16x8*)(kfp + c * 2048 + 512);
            kf2 = *(const bf16x8*)(kfp + c * 2048 + 1024);
            kf3 = *(const bf16x8*)(kfp + c * 2048 + 1536);
            vf0 = *(const bf16x8*)(vfp + c * 2048);
            vf1 = *(const bf16x8*)(vfp + c * 2048 + 512);
            vf2 = *(const bf16x8*)(vfp + c * 2048 + 1024);
            vf3 = *(const bf16x8*)(vfp + c * 2048 + 1536);
            b0 = *(const f32x4*)(fp + c * 32);
            b1 = *(const f32x4*)(fp + c * 32 + 16);
        } else {
            const float* ks = Kb + (size_t)(k0 + c * 32 + lq) * DN + lg * 8;
            #pragma unroll
            for (int j = 0; j < 8; ++j) {
                kf0[j] = f2bf(ks[j]);            kf1[j] = f2bf(ks[32 + j]);
                kf2[j] = f2bf(ks[16 * DN + j]);  kf3[j] = f2bf(ks[16 * DN + 32 + j]);
            }
            #pragma unroll
            for (int j = 0; j < 4; ++j) {
                const float* va = Vb + (size_t)(k0 + c * 32 + 4 * lg + j) * DN + lq;
                const float* vb = Vb + (size_t)(k0 + c * 32 + 16 + 4 * lg + j) * DN + lq;
                vf0[j] = f2bf(va[0]);  vf0[4 + j] = f2bf(vb[0]);
                vf1[j] = f2bf(va[16]); vf1[4 + j] = f2bf(vb[16]);
                vf2[j] = f2bf(va[32]); vf2[4 + j] = f2bf(vb[32]);
                vf3[j] = f2bf(va[48]); vf3[4 + j] = f2bf(vb[48]);
            }
            const i32x4 mv0 = *(const i32x4*)(Mb + k0 + c * 32 + 4 * lg);
            const i32x4 mv1 = *(const i32x4*)(Mb + k0 + c * 32 + 16 + 4 * lg);
            #pragma unroll
            for (int r = 0; r < 4; ++r) {
                b0[r] = mv0[r] ? -BI_L2E : -1e9f;
                b1[r] = mv1[r] ? -BI_L2E : -1e9f;
            }
        }
        f32x4 a0 = {0.f, 0.f, 0.f, 0.f}, a1 = {0.f, 0.f, 0.f, 0.f};
        a0 = __builtin_amdgcn_mfma_f32_16x16x32_bf16(kf0, qf0, a0, 0, 0, 0);
        a0 = __builtin_amdgcn_mfma_f32_16x16x32_bf16(kf1, qf1, a0, 0, 0, 0);
        a1 = __builtin_amdgcn_mfma_f32_16x16x32_bf16(kf2, qf0, a1, 0, 0, 0);
        a1 = __builtin_amdgcn_mfma_f32_16x16x32_bf16(kf3, qf1, a1, 0, 0, 0);

        float p0[4], p1[4];
        #pragma unroll
        for (int r = 0; r < 4; ++r) {
            p0[r] = fast_exp2(fmaf(a0[r], SC_L2E, b0[r]));
            p1[r] = fast_exp2(fmaf(a1[r], SC_L2E, b1[r]));
            lsum += p0[r] + p1[r];
        }
        union { unsigned u[4]; bf16x8 v; } pa;
        pa.u[0] = pk2(p0[0], p0[1]); pa.u[1] = pk2(p0[2], p0[3]);
        pa.u[2] = pk2(p1[0], p1[1]); pa.u[3] = pk2(p1[2], p1[3]);
        pk[c][0] = pa.u[0]; pk[c][1] = pa.u[1];
        pk[c][2] = pa.u[2]; pk[c][3] = pa.u[3];

        // in-place PV: A = packed quads (slot-permuted); Vf built to match
        oacc[0] = __builtin_amdgcn_mfma_f32_16x16x32_bf16(pa.v, vf0, oacc[0], 0, 0, 0);
        oacc[1] = __builtin_amdgcn_mfma_f32_16x16x32_bf16(pa.v, vf1, oacc[1], 0, 0, 0);
        oacc[2] = __builtin_amdgcn_mfma_f32_16x16x32_bf16(pa.v, vf2, oacc[2], 0, 0, 0);
        oacc[3] = __builtin_amdgcn_mfma_f32_16x16x32_bf16(pa.v, vf3, oacc[3], 0, 0, 0);
    }

    // row sums (row = lq): reduce over lg groups, then waves via LDS
    lsum += __shfl_xor(lsum, 16);
    lsum += __shfl_xor(lsum, 32);
    if (lg == 0) lred[wv * QB + lq] = lsum;
    __syncthreads();

    // per-thread rl for its own row lq (reads lred directly; no extra barrier)
    float lrow = 0.f;
    #pragma unroll
    for (int w = 0; w < NWAVE; ++w) lrow += lred[w * QB + lq];
    const float rl = 1.f / lrow;
    if (tid < QB) {
        float l = 0.f;
        #pragma unroll
        for (int w = 0; w < NWAVE; ++w) l += lred[w * QB + tid];
        lfin[tid] = 1.f / l;   // visible to epilogue after barrier2
    }

    // ---- store tail: p_attn = p~ * rl straight from regs (NT, full 64B) ----
    float* pp = out_p + (size_t)lq * SN + k0 + 4 * lg;
    #pragma unroll
    for (int c = 0; c < NCH; ++c) {
        f32x4 o0, o1;
        o0[0] = uf(pk[c][0] << 16) * rl;  o0[1] = uf(pk[c][0] & 0xffff0000u) * rl;
        o0[2] = uf(pk[c][1] << 16) * rl;  o0[3] = uf(pk[c][1] & 0xffff0000u) * rl;
        o1[0] = uf(pk[c][2] << 16) * rl;  o1[1] = uf(pk[c][2] & 0xffff0000u) * rl;
        o1[2] = uf(pk[c][3] << 16) * rl;  o1[3] = uf(pk[c][3] & 0xffff0000u) * rl;
        __builtin_nontemporal_store(o0, (f32x4*)(pp + c * 32));
        __builtin_nontemporal_store(o1, (f32x4*)(pp + c * 32 + 16));
    }

    // ---- cross-wave O reduce, normalize, write ----
    #pragma unroll
    for (int nt = 0; nt < 4; ++nt) {
        #pragma unroll
        for (int r = 0; r < 4; ++r)
            obuf[(wv * QB + 4 * lg + r) * DN + nt * 16 + lq] = oacc[nt][r];
    }
    __syncthreads();
    #pragma unroll
    for (int i = 0; i < 2; ++i) {
        const int idx = tid + i * 512;
        const int q = idx >> 6, d = idx & 63;
        float v = 0.f;
        #pragma unroll
        for (int w = 0; w < NWAVE; ++w) v += obuf[(w * QB + q) * DN + d];
        out_o[(size_t)q * DN + d] = v * lfin[q];
    }
}

extern "C" void kernel_launch(void* const* d_in, const int* in_sizes, int n_in,
                              void* d_out, int out_size, void* d_ws, size_t ws_size,
                              hipStream_t stream) {
    const float* Q = (const float*)d_in[0];
    const float* K = (const float*)d_in[1];
    const float* V = (const float*)d_in[2];
    const int*   M = (const int*)d_in[3];
    float* out = (float*)d_out;

    const size_t szKf = (size_t)BN * 64 * 4 * 512 * sizeof(short);  // 4 MB
    const size_t szVf = szKf;                                       // 4 MB
    const size_t szMf = (size_t)BN * SN * sizeof(float);            // 128 KB
    const size_t need = szKf + szVf + szMf;

    dim3 block(512);
    dim3 grid(BN * (SN / QB));                                      // 2048 blocks
    if (ws_size >= need) {
        short* Kf = (short*)d_ws;
        short* Vf = (short*)((char*)d_ws + szKf);
        float* Mf = (float*)((char*)d_ws + szKf + szVf);
        prep_kv<<<dim3(BN * (SN / 64)), dim3(256), 0, stream>>>(K, V, M, Kf, Vf, Mf);
        attn_fused<1><<<grid, block, 0, stream>>>(Q, K, V, M, Kf, Vf, Mf, out);
    } else {
        attn_fused<0><<<grid, block, 0, stream>>>(Q, K, V, M, nullptr, nullptr, nullptr, out);
    }
}

// Round 12
// 107.863 us; speedup vs baseline: 1.1127x; 1.1127x over previous
//
#include <hip/hip_runtime.h>
#include <hip/hip_bf16.h>

// Attention fwd with materialized p_attn.
// B=16, S=2048, D=64, f32 in/out. d_out = [out (B,S,D) | p_attn (B,S,S)] f32.
#define BN 16
#define SN 2048
#define DN 64
#define QB 16
#define NWAVE 8           // 512 threads
#define KSEG 256          // keys per wave
#define NCH 8             // chunks (32 keys) per wave

#define SC_L2E 0.18033688011112042f   // 0.125 * log2(e)
#define BI_L2E 11.541560327111707f    // 8 * log2(e): p~ = exp(s - 8)

typedef __attribute__((ext_vector_type(8))) short bf16x8;
typedef __attribute__((ext_vector_type(4))) short bf16x4;
typedef __attribute__((ext_vector_type(4))) float f32x4;
typedef __attribute__((ext_vector_type(4))) int   i32x4;

static __device__ __forceinline__ short f2bf(float f) {
    __hip_bfloat16 h = __float2bfloat16(f);
    union { __hip_bfloat16 h; short s; } u; u.h = h;
    return u.s;
}
static __device__ __forceinline__ float uf(unsigned u) {
    union { unsigned u; float f; } v; v.u = u;
    return v.f;
}
static __device__ __forceinline__ unsigned pk2(float lo, float hi) {
    return ((unsigned)(unsigned short)f2bf(lo)) |
           (((unsigned)(unsigned short)f2bf(hi)) << 16);
}
static __device__ __forceinline__ float fast_exp2(float x) {
#if __has_builtin(__builtin_amdgcn_exp2f)
    return __builtin_amdgcn_exp2f(x);
#else
    return exp2f(x);
#endif
}

// ---- prep: swizzle K and V into MFMA-fragment lane order; mask -> f32 bias ----
// (validated in R10)
__global__ __launch_bounds__(256)
void prep_kv(const float* __restrict__ K, const float* __restrict__ V,
             const int* __restrict__ M,
             short* __restrict__ Kf, short* __restrict__ Vf, float* __restrict__ Mf)
{
    __shared__ short vt[64][72];
    const int b   = blockIdx.x >> 5;
    const int s0  = (blockIdx.x & 31) << 6;
    const int cg0 = s0 >> 5;
    const int tid = threadIdx.x;
    const int sr = tid >> 4;
    const int dc = (tid & 15) << 2;
    #pragma unroll
    for (int i = 0; i < 4; ++i) {
        const int s = sr + i * 16;
        f32x4 vv = *(const f32x4*)(V + ((size_t)b * SN + s0 + s) * DN + dc);
        bf16x4 v4;
        #pragma unroll
        for (int j = 0; j < 4; ++j) v4[j] = f2bf(vv[j]);
        *(bf16x4*)&vt[s][dc] = v4;
    }
    if (tid < 64) {
        const int m = M[(size_t)b * SN + s0 + tid];
        Mf[(size_t)b * SN + s0 + tid] = m ? -BI_L2E : -1e9f;
    }
    __syncthreads();

    #pragma unroll
    for (int r = 0; r < 2; ++r) {
        const int o   = tid + (r << 8);
        const int h   = o >> 8;
        const int s   = (o >> 6) & 3;
        const int l2  = o & 63;
        const int lq2 = l2 & 15, lg2 = l2 >> 4;
        const int srow = s0 + h * 32 + ((s >> 1) & 1) * 16 + lq2;
        const int scol = (s & 1) * 32 + lg2 * 8;
        const float* kp = K + ((size_t)b * SN + srow) * DN + scol;
        f32x4 x = *(const f32x4*)kp;
        f32x4 y = *(const f32x4*)(kp + 4);
        bf16x8 kv;
        #pragma unroll
        for (int j = 0; j < 4; ++j) { kv[j] = f2bf(x[j]); kv[4 + j] = f2bf(y[j]); }
        *(bf16x8*)(Kf + (size_t)(((b * 64 + cg0 + h) * 4 + s) * 512 + l2 * 8)) = kv;
    }
    #pragma unroll
    for (int r = 0; r < 2; ++r) {
        const int o   = tid + (r << 8);
        const int h   = o >> 8;
        const int nt  = (o >> 6) & 3;
        const int l2  = o & 63;
        const int lq2 = l2 & 15, lg2 = l2 >> 4;
        const int d   = nt * 16 + lq2;
        bf16x8 w;
        #pragma unroll
        for (int j = 0; j < 4; ++j) {
            w[j]     = vt[h * 32 + 4 * lg2 + j][d];
            w[4 + j] = vt[h * 32 + 16 + 4 * lg2 + j][d];
        }
        *(bf16x8*)(Vf + (size_t)(((b * 64 + cg0 + h) * 4 + nt) * 512 + l2 * 8)) = w;
    }
}

// ---- fused attention (R10 two-pass structure, single barrier) ----
// Pass A: QK^T (mfma(K,Q)) + exp -> pk regs + row-sum. Lean registers: only
// kf + pk live. Barrier. Pass B: PV (slot-permuted in-place A) + NT p-stores;
// only vf + oacc live. rl computed per-thread from lred (no 2nd barrier).
template <int PRE>
__global__ __launch_bounds__(512, 2)
void attn_fused(const float* __restrict__ Q, const float* __restrict__ K,
                const float* __restrict__ V, const int* __restrict__ M,
                const short* __restrict__ Kf, const short* __restrict__ Vf,
                const float* __restrict__ Mf, float* __restrict__ out)
{
    __shared__ float obuf[NWAVE * QB * DN];   // 32 KB (epilogue only)
    __shared__ float lred[NWAVE * QB];
    __shared__ float lfin[QB];

    const int tid = threadIdx.x;
    const int wv = tid >> 6, ln = tid & 63;
    const int lq = ln & 15, lg = ln >> 4;

    // XCD-bijective swizzle (2048 blocks / 8 XCDs): 2 batches per XCD.
    const int lb = ((blockIdx.x & 7) << 8) | (blockIdx.x >> 3);
    const int bb = lb >> 7;
    const int q0 = (lb & 127) << 4;

    const float* Qb = Q + ((size_t)bb * SN + q0) * DN;
    float* out_o = out + ((size_t)bb * SN + q0) * DN;
    float* out_p = out + (size_t)BN * SN * DN + ((size_t)bb * SN + q0) * SN;

    // Q fragment (B-operand of swapped QK^T): Q[col=lq][d=8*lg+j]
    bf16x8 qf0, qf1;
    {
        const float* src = Qb + lq * DN + lg * 8;
        f32x4 a = *(const f32x4*)src;
        f32x4 b = *(const f32x4*)(src + 4);
        f32x4 c = *(const f32x4*)(src + 32);
        f32x4 d = *(const f32x4*)(src + 36);
        #pragma unroll
        for (int j = 0; j < 4; ++j) {
            qf0[j] = f2bf(a[j]); qf0[4 + j] = f2bf(b[j]);
            qf1[j] = f2bf(c[j]); qf1[4 + j] = f2bf(d[j]);
        }
    }

    const int k0 = wv * KSEG;
    const int cgb = bb * 64 + wv * NCH;
    const short* kfp = Kf + (size_t)cgb * 2048 + ln * 8;
    const short* vfp = Vf + (size_t)cgb * 2048 + ln * 8;
    const float* fp  = Mf + (size_t)bb * SN + k0 + 4 * lg;
    const int*   Mb  = M + (size_t)bb * SN;
    const float* Kb  = K + (size_t)bb * SN * DN;
    const float* Vb  = V + (size_t)bb * SN * DN;

    unsigned pk[NCH][4];
    float ls0 = 0.f, ls1 = 0.f;               // split sum chains

    // ================= pass A: QK^T + exp -> registers =================
    #pragma unroll
    for (int c = 0; c < NCH; ++c) {
        bf16x8 kf0, kf1, kf2, kf3;
        f32x4 b0, b1;
        if constexpr (PRE) {
            kf0 = *(const bf16x8*)(kfp + c * 2048);
            kf1 = *(const bf16x8*)(kfp + c * 2048 + 512);
            kf2 = *(const bf16x8*)(kfp + c * 2048 + 1024);
            kf3 = *(const bf16x8*)(kfp + c * 2048 + 1536);
            b0 = *(const f32x4*)(fp + c * 32);
            b1 = *(const f32x4*)(fp + c * 32 + 16);
        } else {
            const float* ks = Kb + (size_t)(k0 + c * 32 + lq) * DN + lg * 8;
            #pragma unroll
            for (int j = 0; j < 8; ++j) {
                kf0[j] = f2bf(ks[j]);            kf1[j] = f2bf(ks[32 + j]);
                kf2[j] = f2bf(ks[16 * DN + j]);  kf3[j] = f2bf(ks[16 * DN + 32 + j]);
            }
            const i32x4 mv0 = *(const i32x4*)(Mb + k0 + c * 32 + 4 * lg);
            const i32x4 mv1 = *(const i32x4*)(Mb + k0 + c * 32 + 16 + 4 * lg);
            #pragma unroll
            for (int r = 0; r < 4; ++r) {
                b0[r] = mv0[r] ? -BI_L2E : -1e9f;
                b1[r] = mv1[r] ? -BI_L2E : -1e9f;
            }
        }
        f32x4 a0 = {0.f, 0.f, 0.f, 0.f}, a1 = {0.f, 0.f, 0.f, 0.f};
        a0 = __builtin_amdgcn_mfma_f32_16x16x32_bf16(kf0, qf0, a0, 0, 0, 0);
        a0 = __builtin_amdgcn_mfma_f32_16x16x32_bf16(kf1, qf1, a0, 0, 0, 0);
        a1 = __builtin_amdgcn_mfma_f32_16x16x32_bf16(kf2, qf0, a1, 0, 0, 0);
        a1 = __builtin_amdgcn_mfma_f32_16x16x32_bf16(kf3, qf1, a1, 0, 0, 0);

        float p0[4], p1[4];
        #pragma unroll
        for (int r = 0; r < 4; ++r) {
            p0[r] = fast_exp2(fmaf(a0[r], SC_L2E, b0[r]));
            p1[r] = fast_exp2(fmaf(a1[r], SC_L2E, b1[r]));
            ls0 += p0[r];
            ls1 += p1[r];
        }
        pk[c][0] = pk2(p0[0], p0[1]); pk[c][1] = pk2(p0[2], p0[3]);
        pk[c][2] = pk2(p1[0], p1[1]); pk[c][3] = pk2(p1[2], p1[3]);
    }

    // row sums (row = lq): reduce over lg groups, then waves via LDS
    float lsum = ls0 + ls1;
    lsum += __shfl_xor(lsum, 16);
    lsum += __shfl_xor(lsum, 32);
    if (lg == 0) lred[wv * QB + lq] = lsum;
    __syncthreads();

    // per-thread rl for row lq directly from lred (no second barrier)
    float lrow = 0.f;
    #pragma unroll
    for (int w = 0; w < NWAVE; ++w) lrow += lred[w * QB + lq];
    const float rl = 1.f / lrow;
    if (tid < QB) {
        float l = 0.f;
        #pragma unroll
        for (int w = 0; w < NWAVE; ++w) l += lred[w * QB + tid];
        lfin[tid] = 1.f / l;   // consumed after the obuf barrier below
    }

    // ================= pass B: PV + p stores from registers =================
    f32x4 oacc[4];
    #pragma unroll
    for (int nt = 0; nt < 4; ++nt) oacc[nt] = (f32x4){0.f, 0.f, 0.f, 0.f};
    float* pp = out_p + (size_t)lq * SN + k0 + 4 * lg;

    #pragma unroll
    for (int c = 0; c < NCH; ++c) {
        union { unsigned u[4]; bf16x8 v; } pa;
        pa.u[0] = pk[c][0]; pa.u[1] = pk[c][1];
        pa.u[2] = pk[c][2]; pa.u[3] = pk[c][3];

        bf16x8 vf0, vf1, vf2, vf3;
        if constexpr (PRE) {
            vf0 = *(const bf16x8*)(vfp + c * 2048);
            vf1 = *(const bf16x8*)(vfp + c * 2048 + 512);
            vf2 = *(const bf16x8*)(vfp + c * 2048 + 1024);
            vf3 = *(const bf16x8*)(vfp + c * 2048 + 1536);
        } else {
            #pragma unroll
            for (int j = 0; j < 4; ++j) {
                const float* va = Vb + (size_t)(k0 + c * 32 + 4 * lg + j) * DN + lq;
                const float* vb = Vb + (size_t)(k0 + c * 32 + 16 + 4 * lg + j) * DN + lq;
                vf0[j] = f2bf(va[0]);  vf0[4 + j] = f2bf(vb[0]);
                vf1[j] = f2bf(va[16]); vf1[4 + j] = f2bf(vb[16]);
                vf2[j] = f2bf(va[32]); vf2[4 + j] = f2bf(vb[32]);
                vf3[j] = f2bf(va[48]); vf3[4 + j] = f2bf(vb[48]);
            }
        }
        oacc[0] = __builtin_amdgcn_mfma_f32_16x16x32_bf16(pa.v, vf0, oacc[0], 0, 0, 0);
        oacc[1] = __builtin_amdgcn_mfma_f32_16x16x32_bf16(pa.v, vf1, oacc[1], 0, 0, 0);
        oacc[2] = __builtin_amdgcn_mfma_f32_16x16x32_bf16(pa.v, vf2, oacc[2], 0, 0, 0);
        oacc[3] = __builtin_amdgcn_mfma_f32_16x16x32_bf16(pa.v, vf3, oacc[3], 0, 0, 0);

        // p_attn = p~ * rl straight from regs; 4 lg-lanes tile full 128B lines
        f32x4 o0, o1;
        o0[0] = uf(pk[c][0] << 16) * rl;  o0[1] = uf(pk[c][0] & 0xffff0000u) * rl;
        o0[2] = uf(pk[c][1] << 16) * rl;  o0[3] = uf(pk[c][1] & 0xffff0000u) * rl;
        o1[0] = uf(pk[c][2] << 16) * rl;  o1[1] = uf(pk[c][2] & 0xffff0000u) * rl;
        o1[2] = uf(pk[c][3] << 16) * rl;  o1[3] = uf(pk[c][3] & 0xffff0000u) * rl;
        __builtin_nontemporal_store(o0, (f32x4*)(pp + c * 32));
        __builtin_nontemporal_store(o1, (f32x4*)(pp + c * 32 + 16));
    }

    // ---- cross-wave O reduce, normalize, write ----
    #pragma unroll
    for (int nt = 0; nt < 4; ++nt) {
        #pragma unroll
        for (int r = 0; r < 4; ++r)
            obuf[(wv * QB + 4 * lg + r) * DN + nt * 16 + lq] = oacc[nt][r];
    }
    __syncthreads();
    #pragma unroll
    for (int i = 0; i < 2; ++i) {
        const int idx = tid + i * 512;
        const int q = idx >> 6, d = idx & 63;
        float v = 0.f;
        #pragma unroll
        for (int w = 0; w < NWAVE; ++w) v += obuf[(w * QB + q) * DN + d];
        out_o[(size_t)q * DN + d] = v * lfin[q];
    }
}

extern "C" void kernel_launch(void* const* d_in, const int* in_sizes, int n_in,
                              void* d_out, int out_size, void* d_ws, size_t ws_size,
                              hipStream_t stream) {
    const float* Q = (const float*)d_in[0];
    const float* K = (const float*)d_in[1];
    const float* V = (const float*)d_in[2];
    const int*   M = (const int*)d_in[3];
    float* out = (float*)d_out;

    const size_t szKf = (size_t)BN * 64 * 4 * 512 * sizeof(short);  // 4 MB
    const size_t szVf = szKf;                                       // 4 MB
    const size_t szMf = (size_t)BN * SN * sizeof(float);            // 128 KB
    const size_t need = szKf + szVf + szMf;

    dim3 block(512);
    dim3 grid(BN * (SN / QB));                                      // 2048 blocks
    if (ws_size >= need) {
        short* Kf = (short*)d_ws;
        short* Vf = (short*)((char*)d_ws + szKf);
        float* Mf = (float*)((char*)d_ws + szKf + szVf);
        prep_kv<<<dim3(BN * (SN / 64)), dim3(256), 0, stream>>>(K, V, M, Kf, Vf, Mf);
        attn_fused<1><<<grid, block, 0, stream>>>(Q, K, V, M, Kf, Vf, Mf, out);
    } else {
        attn_fused<0><<<grid, block, 0, stream>>>(Q, K, V, M, nullptr, nullptr, nullptr, out);
    }
}

// Round 13
// 100.507 us; speedup vs baseline: 1.1941x; 1.0732x over previous
//
#include <hip/hip_runtime.h>
#include <hip/hip_bf16.h>

// Attention fwd with materialized p_attn.
// B=16, S=2048, D=64, f32 in/out. d_out = [out (B,S,D) | p_attn (B,S,S)] f32.
#define BN 16
#define SN 2048
#define DN 64
#define QB 16
#define NWAVE 8           // 512 threads
#define KSEG 256          // keys per wave
#define NCH 8             // chunks (32 keys) per wave; 0-3 in regs, 4-7 in LDS

#define SC_L2E 0.18033688011112042f   // 0.125 * log2(e)
#define BI_L2E 11.541560327111707f    // 8 * log2(e): p~ = exp(s - 8)

typedef __attribute__((ext_vector_type(8))) short bf16x8;
typedef __attribute__((ext_vector_type(4))) short bf16x4;
typedef __attribute__((ext_vector_type(4))) float f32x4;
typedef __attribute__((ext_vector_type(4))) int   i32x4;
typedef __attribute__((ext_vector_type(4))) unsigned u32x4;

static __device__ __forceinline__ short f2bf(float f) {
    __hip_bfloat16 h = __float2bfloat16(f);
    union { __hip_bfloat16 h; short s; } u; u.h = h;
    return u.s;
}
static __device__ __forceinline__ float uf(unsigned u) {
    union { unsigned u; float f; } v; v.u = u;
    return v.f;
}
static __device__ __forceinline__ unsigned pk2(float lo, float hi) {
    return ((unsigned)(unsigned short)f2bf(lo)) |
           (((unsigned)(unsigned short)f2bf(hi)) << 16);
}
static __device__ __forceinline__ float fast_exp2(float x) {
#if __has_builtin(__builtin_amdgcn_exp2f)
    return __builtin_amdgcn_exp2f(x);
#else
    return exp2f(x);
#endif
}

// ---- prep: swizzle K and V into MFMA-fragment lane order; mask -> f32 bias ----
// (validated in R10)
__global__ __launch_bounds__(256)
void prep_kv(const float* __restrict__ K, const float* __restrict__ V,
             const int* __restrict__ M,
             short* __restrict__ Kf, short* __restrict__ Vf, float* __restrict__ Mf)
{
    __shared__ short vt[64][72];
    const int b   = blockIdx.x >> 5;
    const int s0  = (blockIdx.x & 31) << 6;
    const int cg0 = s0 >> 5;
    const int tid = threadIdx.x;
    const int sr = tid >> 4;
    const int dc = (tid & 15) << 2;
    #pragma unroll
    for (int i = 0; i < 4; ++i) {
        const int s = sr + i * 16;
        f32x4 vv = *(const f32x4*)(V + ((size_t)b * SN + s0 + s) * DN + dc);
        bf16x4 v4;
        #pragma unroll
        for (int j = 0; j < 4; ++j) v4[j] = f2bf(vv[j]);
        *(bf16x4*)&vt[s][dc] = v4;
    }
    if (tid < 64) {
        const int m = M[(size_t)b * SN + s0 + tid];
        Mf[(size_t)b * SN + s0 + tid] = m ? -BI_L2E : -1e9f;
    }
    __syncthreads();

    #pragma unroll
    for (int r = 0; r < 2; ++r) {
        const int o   = tid + (r << 8);
        const int h   = o >> 8;
        const int s   = (o >> 6) & 3;
        const int l2  = o & 63;
        const int lq2 = l2 & 15, lg2 = l2 >> 4;
        const int srow = s0 + h * 32 + ((s >> 1) & 1) * 16 + lq2;
        const int scol = (s & 1) * 32 + lg2 * 8;
        const float* kp = K + ((size_t)b * SN + srow) * DN + scol;
        f32x4 x = *(const f32x4*)kp;
        f32x4 y = *(const f32x4*)(kp + 4);
        bf16x8 kv;
        #pragma unroll
        for (int j = 0; j < 4; ++j) { kv[j] = f2bf(x[j]); kv[4 + j] = f2bf(y[j]); }
        *(bf16x8*)(Kf + (size_t)(((b * 64 + cg0 + h) * 4 + s) * 512 + l2 * 8)) = kv;
    }
    #pragma unroll
    for (int r = 0; r < 2; ++r) {
        const int o   = tid + (r << 8);
        const int h   = o >> 8;
        const int nt  = (o >> 6) & 3;
        const int l2  = o & 63;
        const int lq2 = l2 & 15, lg2 = l2 >> 4;
        const int d   = nt * 16 + lq2;
        bf16x8 w;
        #pragma unroll
        for (int j = 0; j < 4; ++j) {
            w[j]     = vt[h * 32 + 4 * lg2 + j][d];
            w[4 + j] = vt[h * 32 + 16 + 4 * lg2 + j][d];
        }
        *(bf16x8*)(Vf + (size_t)(((b * 64 + cg0 + h) * 4 + nt) * 512 + l2 * 8)) = w;
    }
}

// ---- fused attention: two-pass, pk split regs/LDS for 3 blocks/CU ----
// Pass A: QK^T (mfma(K,Q)) + exp -> pk chunks 0-3 in regs, 4-7 ds_write_b128
// to the (idle) obuf region, wave-private lane-contiguous (conflict-free).
// Barrier (lred). Pass B: PV (slot-permuted in-place A) + NT p-stores; chunks
// 4-7 read back via ds_read_b128. Stash region == this wave's obuf region,
// and all stash reads precede obuf writes in wave program order -> safe.
template <int PRE>
__global__ __launch_bounds__(512, 3)
void attn_fused(const float* __restrict__ Q, const float* __restrict__ K,
                const float* __restrict__ V, const int* __restrict__ M,
                const short* __restrict__ Kf, const short* __restrict__ Vf,
                const float* __restrict__ Mf, float* __restrict__ out)
{
    __shared__ float obuf[NWAVE * QB * DN];   // 32 KB: pk stash, then O reduce
    __shared__ float lred[NWAVE * QB];
    __shared__ float lfin[QB];

    const int tid = threadIdx.x;
    const int wv = tid >> 6, ln = tid & 63;
    const int lq = ln & 15, lg = ln >> 4;

    // XCD-bijective swizzle (2048 blocks / 8 XCDs): 2 batches per XCD.
    const int lb = ((blockIdx.x & 7) << 8) | (blockIdx.x >> 3);
    const int bb = lb >> 7;
    const int q0 = (lb & 127) << 4;

    const float* Qb = Q + ((size_t)bb * SN + q0) * DN;
    float* out_o = out + ((size_t)bb * SN + q0) * DN;
    float* out_p = out + (size_t)BN * SN * DN + ((size_t)bb * SN + q0) * SN;

    // wave-private pk stash: wv*4KB + c_hi*1KB + ln*16B (lane-contiguous b128)
    u32x4* stash = (u32x4*)obuf + (wv << 8) + ln;   // + c_hi*64 per chunk

    // Q fragment (B-operand of swapped QK^T): Q[col=lq][d=8*lg+j]
    bf16x8 qf0, qf1;
    {
        const float* src = Qb + lq * DN + lg * 8;
        f32x4 a = *(const f32x4*)src;
        f32x4 b = *(const f32x4*)(src + 4);
        f32x4 c = *(const f32x4*)(src + 32);
        f32x4 d = *(const f32x4*)(src + 36);
        #pragma unroll
        for (int j = 0; j < 4; ++j) {
            qf0[j] = f2bf(a[j]); qf0[4 + j] = f2bf(b[j]);
            qf1[j] = f2bf(c[j]); qf1[4 + j] = f2bf(d[j]);
        }
    }

    const int k0 = wv * KSEG;
    const int cgb = bb * 64 + wv * NCH;
    const short* kfp = Kf + (size_t)cgb * 2048 + ln * 8;
    const short* vfp = Vf + (size_t)cgb * 2048 + ln * 8;
    const float* fp  = Mf + (size_t)bb * SN + k0 + 4 * lg;
    const int*   Mb  = M + (size_t)bb * SN;
    const float* Kb  = K + (size_t)bb * SN * DN;
    const float* Vb  = V + (size_t)bb * SN * DN;

    unsigned pk_lo[4][4];                     // chunks 0-3 only
    float ls0 = 0.f, ls1 = 0.f;

    // ================= pass A: QK^T + exp -> regs / LDS stash =================
    #pragma unroll
    for (int c = 0; c < NCH; ++c) {
        bf16x8 kf0, kf1, kf2, kf3;
        f32x4 b0, b1;
        if constexpr (PRE) {
            kf0 = *(const bf16x8*)(kfp + c * 2048);
            kf1 = *(const bf16x8*)(kfp + c * 2048 + 512);
            kf2 = *(const bf16x8*)(kfp + c * 2048 + 1024);
            kf3 = *(const bf16x8*)(kfp + c * 2048 + 1536);
            b0 = *(const f32x4*)(fp + c * 32);
            b1 = *(const f32x4*)(fp + c * 32 + 16);
        } else {
            const float* ks = Kb + (size_t)(k0 + c * 32 + lq) * DN + lg * 8;
            #pragma unroll
            for (int j = 0; j < 8; ++j) {
                kf0[j] = f2bf(ks[j]);            kf1[j] = f2bf(ks[32 + j]);
                kf2[j] = f2bf(ks[16 * DN + j]);  kf3[j] = f2bf(ks[16 * DN + 32 + j]);
            }
            const i32x4 mv0 = *(const i32x4*)(Mb + k0 + c * 32 + 4 * lg);
            const i32x4 mv1 = *(const i32x4*)(Mb + k0 + c * 32 + 16 + 4 * lg);
            #pragma unroll
            for (int r = 0; r < 4; ++r) {
                b0[r] = mv0[r] ? -BI_L2E : -1e9f;
                b1[r] = mv1[r] ? -BI_L2E : -1e9f;
            }
        }
        f32x4 a0 = {0.f, 0.f, 0.f, 0.f}, a1 = {0.f, 0.f, 0.f, 0.f};
        a0 = __builtin_amdgcn_mfma_f32_16x16x32_bf16(kf0, qf0, a0, 0, 0, 0);
        a0 = __builtin_amdgcn_mfma_f32_16x16x32_bf16(kf1, qf1, a0, 0, 0, 0);
        a1 = __builtin_amdgcn_mfma_f32_16x16x32_bf16(kf2, qf0, a1, 0, 0, 0);
        a1 = __builtin_amdgcn_mfma_f32_16x16x32_bf16(kf3, qf1, a1, 0, 0, 0);

        float p0[4], p1[4];
        #pragma unroll
        for (int r = 0; r < 4; ++r) {
            p0[r] = fast_exp2(fmaf(a0[r], SC_L2E, b0[r]));
            p1[r] = fast_exp2(fmaf(a1[r], SC_L2E, b1[r]));
            ls0 += p0[r];
            ls1 += p1[r];
        }
        u32x4 w;
        w[0] = pk2(p0[0], p0[1]); w[1] = pk2(p0[2], p0[3]);
        w[2] = pk2(p1[0], p1[1]); w[3] = pk2(p1[2], p1[3]);
        if (c < 4) {
            pk_lo[c][0] = w[0]; pk_lo[c][1] = w[1];
            pk_lo[c][2] = w[2]; pk_lo[c][3] = w[3];
        } else {
            stash[(c - 4) << 6] = w;          // ds_write_b128, wave-private
        }
    }

    // row sums (row = lq): reduce over lg groups, then waves via LDS
    float lsum = ls0 + ls1;
    lsum += __shfl_xor(lsum, 16);
    lsum += __shfl_xor(lsum, 32);
    if (lg == 0) lred[wv * QB + lq] = lsum;
    __syncthreads();

    float lrow = 0.f;
    #pragma unroll
    for (int w = 0; w < NWAVE; ++w) lrow += lred[w * QB + lq];
    const float rl = 1.f / lrow;
    if (tid < QB) {
        float l = 0.f;
        #pragma unroll
        for (int w = 0; w < NWAVE; ++w) l += lred[w * QB + tid];
        lfin[tid] = 1.f / l;   // consumed after the obuf barrier below
    }

    // ================= pass B: PV + p stores =================
    f32x4 oacc[4];
    #pragma unroll
    for (int nt = 0; nt < 4; ++nt) oacc[nt] = (f32x4){0.f, 0.f, 0.f, 0.f};
    float* pp = out_p + (size_t)lq * SN + k0 + 4 * lg;

    #pragma unroll
    for (int c = 0; c < NCH; ++c) {
        union { unsigned u[4]; u32x4 w; bf16x8 v; } pa;
        if (c < 4) {
            pa.u[0] = pk_lo[c][0]; pa.u[1] = pk_lo[c][1];
            pa.u[2] = pk_lo[c][2]; pa.u[3] = pk_lo[c][3];
        } else {
            pa.w = stash[(c - 4) << 6];       // ds_read_b128, wave-private
        }

        bf16x8 vf0, vf1, vf2, vf3;
        if constexpr (PRE) {
            vf0 = *(const bf16x8*)(vfp + c * 2048);
            vf1 = *(const bf16x8*)(vfp + c * 2048 + 512);
            vf2 = *(const bf16x8*)(vfp + c * 2048 + 1024);
            vf3 = *(const bf16x8*)(vfp + c * 2048 + 1536);
        } else {
            #pragma unroll
            for (int j = 0; j < 4; ++j) {
                const float* va = Vb + (size_t)(k0 + c * 32 + 4 * lg + j) * DN + lq;
                const float* vb = Vb + (size_t)(k0 + c * 32 + 16 + 4 * lg + j) * DN + lq;
                vf0[j] = f2bf(va[0]);  vf0[4 + j] = f2bf(vb[0]);
                vf1[j] = f2bf(va[16]); vf1[4 + j] = f2bf(vb[16]);
                vf2[j] = f2bf(va[32]); vf2[4 + j] = f2bf(vb[32]);
                vf3[j] = f2bf(va[48]); vf3[4 + j] = f2bf(vb[48]);
            }
        }
        oacc[0] = __builtin_amdgcn_mfma_f32_16x16x32_bf16(pa.v, vf0, oacc[0], 0, 0, 0);
        oacc[1] = __builtin_amdgcn_mfma_f32_16x16x32_bf16(pa.v, vf1, oacc[1], 0, 0, 0);
        oacc[2] = __builtin_amdgcn_mfma_f32_16x16x32_bf16(pa.v, vf2, oacc[2], 0, 0, 0);
        oacc[3] = __builtin_amdgcn_mfma_f32_16x16x32_bf16(pa.v, vf3, oacc[3], 0, 0, 0);

        // p_attn = p~ * rl; 4 lg-lanes tile one full 128B line per row
        f32x4 o0, o1;
        o0[0] = uf(pa.u[0] << 16) * rl;  o0[1] = uf(pa.u[0] & 0xffff0000u) * rl;
        o0[2] = uf(pa.u[1] << 16) * rl;  o0[3] = uf(pa.u[1] & 0xffff0000u) * rl;
        o1[0] = uf(pa.u[2] << 16) * rl;  o1[1] = uf(pa.u[2] & 0xffff0000u) * rl;
        o1[2] = uf(pa.u[3] << 16) * rl;  o1[3] = uf(pa.u[3] & 0xffff0000u) * rl;
        __builtin_nontemporal_store(o0, (f32x4*)(pp + c * 32));
        __builtin_nontemporal_store(o1, (f32x4*)(pp + c * 32 + 16));
    }

    // ---- cross-wave O reduce, normalize, write ----
    // (this wave's stash fully consumed above; obuf overwrite is wave-private)
    #pragma unroll
    for (int nt = 0; nt < 4; ++nt) {
        #pragma unroll
        for (int r = 0; r < 4; ++r)
            obuf[(wv * QB + 4 * lg + r) * DN + nt * 16 + lq] = oacc[nt][r];
    }
    __syncthreads();
    #pragma unroll
    for (int i = 0; i < 2; ++i) {
        const int idx = tid + i * 512;
        const int q = idx >> 6, d = idx & 63;
        float v = 0.f;
        #pragma unroll
        for (int w = 0; w < NWAVE; ++w) v += obuf[(w * QB + q) * DN + d];
        out_o[(size_t)q * DN + d] = v * lfin[q];
    }
}

extern "C" void kernel_launch(void* const* d_in, const int* in_sizes, int n_in,
                              void* d_out, int out_size, void* d_ws, size_t ws_size,
                              hipStream_t stream) {
    const float* Q = (const float*)d_in[0];
    const float* K = (const float*)d_in[1];
    const float* V = (const float*)d_in[2];
    const int*   M = (const int*)d_in[3];
    float* out = (float*)d_out;

    const size_t szKf = (size_t)BN * 64 * 4 * 512 * sizeof(short);  // 4 MB
    const size_t szVf = szKf;                                       // 4 MB
    const size_t szMf = (size_t)BN * SN * sizeof(float);            // 128 KB
    const size_t need = szKf + szVf + szMf;

    dim3 block(512);
    dim3 grid(BN * (SN / QB));                                      // 2048 blocks
    if (ws_size >= need) {
        short* Kf = (short*)d_ws;
        short* Vf = (short*)((char*)d_ws + szKf);
        float* Mf = (float*)((char*)d_ws + szKf + szVf);
        prep_kv<<<dim3(BN * (SN / 64)), dim3(256), 0, stream>>>(K, V, M, Kf, Vf, Mf);
        attn_fused<1><<<grid, block, 0, stream>>>(Q, K, V, M, Kf, Vf, Mf, out);
    } else {
        attn_fused<0><<<grid, block, 0, stream>>>(Q, K, V, M, nullptr, nullptr, nullptr, out);
    }
}